// Round 5
// baseline (95.062 us; speedup 1.0000x reference)
//
#include <hip/hip_runtime.h>
#include <math.h>

#define N 4096
#define T 64                // tile size = wave size
#define NT (N / T)          // 64 tiles
#define NSLOT (NT * 2)      // 128 partial slots per row (2 k-halves per tile)
#define FEPS 1e-7f
#define HEPS 5e-8f          // FEPS/2, split across the two records of a pair
#define BLK 256
#define KATAN 0.6366197723675814f   // 2/pi (folds 4/pi^2 into atan)
#define SQL2E 1.2011224087864498f   // sqrt(log2 e), folds exp->exp2 into conf
#define ISQL2E 0.8325546111576977f  // 1/SQL2E, unfolds the cf2 in row-a0

// d_ws: part[slot][c][i] : NSLOT*6*N floats = 12.6 MB. [c][i] innermost ->
// all partial stores and epilogue loads are lane-contiguous (coalesced).

// r5 (after r0=83.9, r1=86.2, r2=95.9, r3=93.9, r4=83.7 all ~neutral):
// main kernel invariant at ~36us = 3.5x its VALU-issue floor across every
// broadcast-pipe / traffic / prefetch variant; only op-count moved time
// (r2: +12 ops/iter -> +12us). Stop optimizing the iteration: HALVE the
// iterations. s_ij is SYMMETRIC (iou, rho2, c2, v, alpha all symmetric ->
// e_ij = e_ji). One wave per 64x64 tile-job; off-diag jobs (ta<tb) compute
// each pair once and feed BOTH row-acc and col-acc:
//   lane l: fixed row-record (ta*64+l); col-record + col-accs ROTATE one
//   lane per iteration (ds_bpermute pull from lane+1). At iter k, lane l
//   processes (row l, col l+k0+k), and the col-acc resident in lane l is
//   exactly that column's -> both accumulations are lane-local, no pushes.
//   Proof of binding: acc born in lane l0 for col l0+k0 sits in lane l0-k
//   after k rotations; lane l0-k at iter k processes col (l0-k)+k0+k =
//   l0+k0. Coverage of col c: kh=0 rows {c-31..c}, kh=1 rows {c-63..c-32}.
// Diag jobs (1.6% of work): 64 rotations, row-accs only (covers tile once),
// col-acc results discarded, zeros written to the paired slot (workspace is
// poisoned -> unwritten slots must be explicitly zeroed).
// Jobs: 64 diag + 2016 pairs x 2 halves = 4096 waves = 1024 blocks.
//
// Kept (measured absmax=0 through r4): one-rcp common-denominator CIoU
//   P = (v+1+eps)*uni - inter (= den*uni, clamped >=1e-12 vs cancellation;
//   cancels exactly in the ratio on the diagonal), ciou = num/(uni*c2*P);
// eps/atan/exp2 foldings. NO 2nd __launch_bounds__ arg (measured: (256,4)
// forced VGPR=64 + ~90MB scratch spills).
__device__ __forceinline__ float bperm(int addr, float v) {
    return __int_as_float(__builtin_amdgcn_ds_bpermute(addr, __float_as_int(v)));
}

__global__ __launch_bounds__(BLK) void ciou_sym_kernel(
        const float* __restrict__ x,
        float* __restrict__ part) {
    const int lane = threadIdx.x & 63;
    const int w = blockIdx.x * (BLK / 64) + (threadIdx.x >> 6);  // wave id 0..4095

    // Job decode (wave-uniform).
    int ta, tb, k0, iters, diag;
    if (w < NT) {
        ta = w; tb = w; k0 = 0; iters = T; diag = 1;
    } else {
        int m = w - NT;
        int p = m >> 1, kh = m & 1;
        int a = 0, rem = p;                 // triangular unrank: p -> (ta<tb)
        while (rem >= NT - 1 - a) { rem -= NT - 1 - a; a++; }
        ta = a; tb = a + 1 + rem; k0 = kh << 5; iters = 32; diag = 0;
    }
    const int kh = k0 >> 5;
    const int slot_row = diag ? (ta * 2)     : (tb * 2 + kh);
    const int slot_col = diag ? (ta * 2 + 1) : (ta * 2 + kh);

    // Row record (lane-fixed).
    const int i = ta * T + lane;
    const float rcf = x[i * 5 + 0];
    const float rx1 = x[i * 5 + 1], ry1 = x[i * 5 + 2];
    const float rx2 = x[i * 5 + 3], ry2 = x[i * 5 + 4];
    const float rw = rx2 - rx1, rh = ry2 - ry1;
    const float rhx = (rx1 + rx2) * 0.5f, rhy = (ry1 + ry2) * 0.5f;
    const float rareps = fmaf(rw, rh, HEPS);
    const float rat = KATAN * atanf(rw / (rh + FEPS));
    const float rcf2 = rcf * SQL2E;

    // Col record (rotating): initial column (lane + k0) & 63 of tile tb.
    const int j = tb * T + ((lane + k0) & 63);
    float jx1 = x[j * 5 + 1], jy1 = x[j * 5 + 2];
    float jx2 = x[j * 5 + 3], jy2 = x[j * 5 + 4];
    float jat = KATAN * atanf((jx2 - jx1) / ((jy2 - jy1) + FEPS));
    float jcf2 = x[j * 5 + 0] * SQL2E;

    const int nxt = ((lane + 1) & 63) * 4;   // bpermute byte-addr: pull lane+1
    const float ONEP = 1.f + FEPS;

    float rs = 0.f, r0 = 0.f, r1 = 0.f, r2 = 0.f, r3 = 0.f, r4 = 0.f;  // row
    float cs = 0.f, c0 = 0.f, c1 = 0.f, c2a = 0.f, c3 = 0.f, c4 = 0.f; // col

#pragma unroll 2
    for (int k = 0; k < iters; k++) {
        // Derive col fields from the 6 rotating ones.
        float jw = jx2 - jx1, jh = jy2 - jy1;
        float jareps = fmaf(jw, jh, HEPS);
        float dx = fmaf(0.5f, jx1 + jx2, -rhx);   // /4 of rho2 pre-folded
        float dy = fmaf(0.5f, jy1 + jy2, -rhy);

        float iwr = fminf(rx2, jx2) - fmaxf(rx1, jx1);
        float ihr = fminf(ry2, jy2) - fmaxf(ry1, jy1);
        float inter = fmaxf(iwr, 0.f) * fmaxf(ihr, 0.f);
        float uni = (rareps + jareps) - inter;
        float cw = (rw + jw) - iwr;               // enclosing box identity
        float chh = (rh + jh) - ihr;
        float c2 = fmaf(cw, cw, fmaf(chh, chh, FEPS));
        float rho2 = fmaf(dx, dx, dy * dy);
        float da = jat - rat;                     // 4/pi^2 pre-folded
        float v = da * da;
        float P = fmaf(v + ONEP, uni, -inter);    // den*uni
        P = fmaxf(P, 1e-12f);                     // fp-cancellation guard
        float rr = __builtin_amdgcn_rcpf(uni * c2 * P);   // ONE rcp
        float t1 = fmaf(inter, c2, -(rho2 * uni));
        float vu = v * uni;
        float num = fmaf(t1, P, -((vu * vu) * c2));
        float e = __builtin_amdgcn_exp2f((num * rr) * (rcf2 * jcf2));

        rs += e;                       // row accs (lane-local row)
        r0 = fmaf(e, jcf2, r0);        // cf2-folded; unfold after loop
        r1 = fmaf(e, jx1, r1);
        r2 = fmaf(e, jy1, r2);
        r3 = fmaf(e, jx2, r3);
        r4 = fmaf(e, jy2, r4);

        cs += e;                       // col accs (resident col, see proof)
        c0 = fmaf(e, rcf, c0);
        c1 = fmaf(e, rx1, c1);
        c2a = fmaf(e, ry1, c2a);
        c3 = fmaf(e, rx2, c3);
        c4 = fmaf(e, ry2, c4);

        // Rotate col record + col accs down one lane (pull from lane+1).
        jx1 = bperm(nxt, jx1); jy1 = bperm(nxt, jy1);
        jx2 = bperm(nxt, jx2); jy2 = bperm(nxt, jy2);
        jat = bperm(nxt, jat); jcf2 = bperm(nxt, jcf2);
        cs = bperm(nxt, cs);   c0 = bperm(nxt, c0);  c1 = bperm(nxt, c1);
        c2a = bperm(nxt, c2a); c3 = bperm(nxt, c3);  c4 = bperm(nxt, c4);
    }

    // Row partials: row i, slot_row. [c][i] layout -> coalesced.
    r0 *= ISQL2E;
    float* pr = part + (size_t)slot_row * 6 * N;
    pr[0 * N + i] = rs; pr[1 * N + i] = r0; pr[2 * N + i] = r1;
    pr[3 * N + i] = r2; pr[4 * N + i] = r3; pr[5 * N + i] = r4;

    // Col partials: after `iters` rotations, lane l holds the acc of column
    // (l + k0 + iters) & 63. Diag: discard accs, write zeros (ws is poisoned).
    const int jr = tb * T + ((lane + k0 + iters) & 63);
    float* pc = part + (size_t)slot_col * 6 * N;
    if (diag) { cs = c0 = c1 = c2a = c3 = c4 = 0.f; }
    pc[0 * N + jr] = cs; pc[1 * N + jr] = c0; pc[2 * N + jr] = c1;
    pc[3 * N + jr] = c2a; pc[4 * N + jr] = c3; pc[5 * N + jr] = c4;
}

// One thread per output element (i,c): sum NSLOT partials, softmax-divide,
// sigmoid. All loads lane-contiguous in i per slot.
__global__ void epilogue_kernel(const float* __restrict__ x,
                                const float* __restrict__ gamma,
                                const float* __restrict__ part,
                                float* __restrict__ out) {
    int idx = blockIdx.x * blockDim.x + threadIdx.x;
    if (idx >= N * 5) return;
    int i = idx / 5, c = idx % 5;
    float se = 0.f, a = 0.f;
#pragma unroll 8
    for (int s = 0; s < NSLOT; s++) {
        se += part[((size_t)s * 6 + 0) * N + i];
        a  += part[((size_t)s * 6 + 1 + c) * N + i];
    }
    float xp = x[idx] * gamma[0] + a / se;
    out[idx] = 1.f / (1.f + expf(-xp));
}

extern "C" void kernel_launch(void* const* d_in, const int* in_sizes, int n_in,
                              void* d_out, int out_size, void* d_ws, size_t ws_size,
                              hipStream_t stream) {
    const float* x = (const float*)d_in[0];
    const float* gamma = (const float*)d_in[1];
    float* out = (float*)d_out;
    float* part = (float*)d_ws;  // NSLOT*6*N floats = 12.6 MB

    // 4096 wave-jobs (64 diag + 2016 pairs x 2 halves) = 1024 blocks of 4 waves.
    ciou_sym_kernel<<<(NT + 2 * (NT * (NT - 1) / 2)) / (BLK / 64), BLK, 0, stream>>>(x, part);
    epilogue_kernel<<<(N * 5 + 255) / 256, 256, 0, stream>>>(x, gamma, part, out);
}

// Round 6
// 91.200 us; speedup vs baseline: 1.0423x; 1.0423x over previous
//
#include <hip/hip_runtime.h>
#include <math.h>

#define N 4096
#define FEPS 1e-7f
#define HEPS 5e-8f      // FEPS/2, split across the two records of a pair
#define BLK 256
#define JT 128          // grid = 16*128 = 2048 blocks = 8 blocks/CU = 8 waves/SIMD
#define CH (N / JT)     // 32 j's staged in LDS per block
#define N6 (N * 6)
#define KATAN 0.6366197723675814f   // 2/pi (folds 4/pi^2 into atan)
#define SQL2E 1.2011224087864498f   // sqrt(log2 e), folds exp->exp2 into conf

// d_ws: part[jt][i*6+k] : JT*N*6 floats = 12.6 MB.

// History (measured): r0=83.9 (LDS b32 broadcast), r1=86.2 (uniform VMEM),
// r2=95.9 (readlane, +12 inst/iter -> +12.7us), r3=93.9 (4-row amortize,
// 2 waves/SIMD), r4=83.7 (prefetch + 1-rcp), r5=95.1 (symmetry-halved pairs
// but ~2x inst/iter). Empirical law fitting ALL points: time ~ wave-iters x
// inst/iter x ~6.6cy/inst -- 3.3x the SIMD-32 issue rate, invariant to pipe
// choice/LDS volume/prefetch. Suspect: only 4 waves/SIMD in every prior
// geometry; serial CIoU dep-chain (~5-6cy/op) leaves issue slots empty.
// r6: 8 waves/SIMD (JT=128, 2048 blocks, __launch_bounds__(256,8) forcing
// VGPR<=64). Slim structure to fit 64 VGPR: no prefetch (measured neutral
// r4), one-rcp math, unroll 2. Live state ~17 persistent + ~22 transient.
//
// Kept (measured absmax=0 through r5): one-rcp common-denominator CIoU:
//   P = (v+1+eps)*uni - inter (= den*uni; >=eps*uni; clamped vs fp
//   cancellation -- cancels exactly in the ratio on the diagonal),
//   ciou = [P*(inter*c2 - rho2*uni) - v^2*uni^2*c2] / (uni*c2*P);
// eps split across records, 4/pi^2 folded into atan, log2e folded into conf.
__global__ __launch_bounds__(BLK, 8) void ciou_attn_kernel(
        const float* __restrict__ x,
        float* __restrict__ part) {
    // 12-float record per j, three aligned float4s:
    // A=[x1,y1,x2,y2]  B=[hx,hy,w,h]  C=[area+eps/2, atan_folded, cf2, cf]
    __shared__ float4 jrec[CH * 3];   // 1.5 KB
    const int tid = threadIdx.x;
    const int gb = blockIdx.x / JT;
    const int jt = blockIdx.x % JT;
    const int i = gb * BLK + tid;

    if (tid < CH) {
        int j = jt * CH + tid;
        float cf = x[j * 5 + 0], jx1 = x[j * 5 + 1], jy1 = x[j * 5 + 2];
        float jx2 = x[j * 5 + 3], jy2 = x[j * 5 + 4];
        float w = jx2 - jx1, h = jy2 - jy1;
        jrec[tid * 3 + 0] = make_float4(jx1, jy1, jx2, jy2);
        jrec[tid * 3 + 1] = make_float4((jx1 + jx2) * 0.5f, (jy1 + jy2) * 0.5f, w, h);
        jrec[tid * 3 + 2] = make_float4(fmaf(w, h, HEPS),
                                        KATAN * atanf(w / (h + FEPS)),
                                        cf * SQL2E, cf);
    }

    // Per-lane row record (11 persistent regs).
    const float rx1 = x[i * 5 + 1], ry1 = x[i * 5 + 2];
    const float rx2 = x[i * 5 + 3], ry2 = x[i * 5 + 4];
    const float rw = rx2 - rx1, rh = ry2 - ry1;
    const float rhx = (rx1 + rx2) * 0.5f, rhy = (ry1 + ry2) * 0.5f;
    const float rareps = fmaf(rw, rh, HEPS);
    const float rat = KATAN * atanf(rw / (rh + FEPS));
    const float rcf2 = x[i * 5 + 0] * SQL2E;

    __syncthreads();

    float sum = 0.f, a0 = 0.f, a1 = 0.f, a2 = 0.f, a3 = 0.f, a4 = 0.f;
    const float ONEP = 1.f + FEPS;

#pragma unroll 2
    for (int jj = 0; jj < CH; jj++) {
        const float4 A = jrec[jj * 3 + 0];
        const float4 B = jrec[jj * 3 + 1];
        const float4 C = jrec[jj * 3 + 2];

        float iwr = fminf(rx2, A.z) - fmaxf(rx1, A.x);
        float ihr = fminf(ry2, A.w) - fmaxf(ry1, A.y);
        float inter = fmaxf(iwr, 0.f) * fmaxf(ihr, 0.f);
        float uni = (rareps + C.x) - inter;
        float cw = (rw + B.z) - iwr;             // enclosing box identity
        float chh = (rh + B.w) - ihr;
        float c2 = fmaf(cw, cw, fmaf(chh, chh, FEPS));
        float dx = B.x - rhx;
        float dy = B.y - rhy;
        float rho2 = fmaf(dx, dx, dy * dy);      // /4 pre-folded
        float da = C.y - rat;                    // 4/pi^2 pre-folded
        float v = da * da;
        float P = fmaf(v + ONEP, uni, -inter);   // den*uni
        P = fmaxf(P, 1e-12f);                    // fp-cancellation guard
        float rr = __builtin_amdgcn_rcpf(uni * c2 * P);   // ONE rcp per pair
        float t1 = fmaf(inter, c2, -(rho2 * uni));
        float vu = v * uni;
        float num = fmaf(t1, P, -((vu * vu) * c2));
        float e = __builtin_amdgcn_exp2f((num * rr) * (rcf2 * C.z));
        sum += e;
        a0 = fmaf(e, C.w, a0);
        a1 = fmaf(e, A.x, a1);
        a2 = fmaf(e, A.y, a2);
        a3 = fmaf(e, A.z, a3);
        a4 = fmaf(e, A.w, a4);
    }

    float* p = part + (size_t)jt * N6 + (size_t)i * 6;
    p[0] = sum; p[1] = a0; p[2] = a1; p[3] = a2; p[4] = a3; p[5] = a4;
}

// One thread per output element (i,c): sum JT partials, softmax-divide, sigmoid.
__global__ void epilogue_kernel(const float* __restrict__ x,
                                const float* __restrict__ gamma,
                                const float* __restrict__ part,
                                float* __restrict__ out) {
    int idx = blockIdx.x * blockDim.x + threadIdx.x;
    if (idx >= N * 5) return;
    int i = idx / 5, c = idx % 5;
    float se = 0.f, a = 0.f;
    const float* p = part + (size_t)i * 6;
#pragma unroll 8
    for (int jt = 0; jt < JT; jt++) {
        se += p[jt * (size_t)N6 + 0];
        a  += p[jt * (size_t)N6 + 1 + c];
    }
    float xp = x[idx] * gamma[0] + a / se;
    out[idx] = 1.f / (1.f + expf(-xp));
}

extern "C" void kernel_launch(void* const* d_in, const int* in_sizes, int n_in,
                              void* d_out, int out_size, void* d_ws, size_t ws_size,
                              hipStream_t stream) {
    const float* x = (const float*)d_in[0];
    const float* gamma = (const float*)d_in[1];
    float* out = (float*)d_out;
    float* part = (float*)d_ws;  // JT*N*6 floats = 12.6 MB

    ciou_attn_kernel<<<(N / BLK) * JT, BLK, 0, stream>>>(x, part);
    epilogue_kernel<<<(N * 5 + 255) / 256, 256, 0, stream>>>(x, gamma, part, out);
}

// Round 7
// 83.469 us; speedup vs baseline: 1.1389x; 1.0926x over previous
//
#include <hip/hip_runtime.h>
#include <math.h>

#define N 4096
#define FEPS 1e-7f
#define HEPS 5e-8f      // FEPS/2, split across the two records of a pair
#define BLK 256
#define JT 64           // grid = 16*64 = 1024 blocks = 4 blocks/CU = 4 waves/SIMD
#define CH 64           // j's per block
#define NPAIR (CH / 2)  // 32 packed j-pairs per block
#define N6 (N * 6)
#define KATAN 0.6366197723675814f   // 2/pi (folds 4/pi^2 into atan)
#define SQL2E 1.2011224087864498f   // sqrt(log2 e), folds exp->exp2 into conf

typedef float v2f __attribute__((ext_vector_type(2)));

// d_ws: part[jt][i*6+k]          : JT*N*6 floats = 6.29 MB
//       feat_row[i][12]          : 196 KB   (plain per-row records)
//       feat_pair[p][24]         : 196 KB   (packed-SoA j-pair records)
//
// r7 (history: r0=83.9 r1=86.2 r2=95.9 r3=93.9 r4=83.7 r5=95.1 r6=91.2):
// every pipe/latency/occupancy theory was neutral-or-worse; the ONLY knob
// that ever moved time as predicted is ISSUED INSTRUCTION COUNT (r2 +12
// inst/iter -> +12.7us; r5 +60% inst/pair -> +11us). So cut it directly:
//  1. packed f32: process 2 j's per iter as float2 ext-vectors -> LLVM
//     forms v_pk_{fma,add,mul}_f32 (dual-rate VOP3P) for ~30 of 45
//     ops/pair; min/max + rcp/exp2 stay scalar. ~102 -> ~55 inst / 2 pairs.
//  2. records precomputed ONCE in feat_kernel (4096 atanf) instead of
//     ~327k per-block recomputations (r6 showed the prologue atanf+scalar
//     loads are a measurable term). Main prologue: 3 coalesced float4 row
//     loads + 3KB LDS memcpy of pre-packed j-pair records.
// Geometry/epilogue unchanged from the 83.7 best (r4).
//
// Kept (absmax=0 through r6): one-rcp common-denominator CIoU
//   P=(v+1+eps)*uni-inter (=den*uni, clamp>=1e-12; cancels in ratio on the
//   diagonal), ciou=[P*(inter*c2-rho2*uni)-v^2*uni^2*c2]/(uni*c2*P);
// eps split across records, 4/pi^2 in atan, log2e in conf.
// NO 2nd __launch_bounds__ arg (measured: forcing waves/EU spills).

// Per-box record fields: 0:x1 1:y1 2:x2 3:y2 4:hx 5:hy 6:w 7:h
// 8:area+eps/2 9:atan-folded 10:cf*sqrt(log2e) 11:cf
__global__ void feat_kernel(const float* __restrict__ x,
                            float* __restrict__ feat_row,
                            float* __restrict__ feat_pair) {
    int i = blockIdx.x * blockDim.x + threadIdx.x;
    if (i >= N) return;
    float cf = x[i * 5 + 0], x1 = x[i * 5 + 1], y1 = x[i * 5 + 2];
    float x2 = x[i * 5 + 3], y2 = x[i * 5 + 4];
    float w = x2 - x1, h = y2 - y1;
    float rec[12];
    rec[0] = x1; rec[1] = y1; rec[2] = x2; rec[3] = y2;
    rec[4] = (x1 + x2) * 0.5f; rec[5] = (y1 + y2) * 0.5f;
    rec[6] = w; rec[7] = h;
    rec[8] = fmaf(w, h, HEPS);
    rec[9] = KATAN * atanf(w / (h + FEPS));
    rec[10] = cf * SQL2E; rec[11] = cf;
    // Row table: 3x float4 (48B stride, 16-aligned).
    float4* dr = (float4*)(feat_row + (size_t)i * 12);
    dr[0] = make_float4(rec[0], rec[1], rec[2], rec[3]);
    dr[1] = make_float4(rec[4], rec[5], rec[6], rec[7]);
    dr[2] = make_float4(rec[8], rec[9], rec[10], rec[11]);
    // Pair table: pair p = i>>1, slot i&1; field k at [p*24 + k*2 + slot].
    float* dp = feat_pair + (size_t)(i >> 1) * 24 + (i & 1);
#pragma unroll
    for (int k = 0; k < 12; k++) dp[k * 2] = rec[k];
}

__device__ __forceinline__ v2f min2(v2f a, v2f b) {
    v2f r; r.x = fminf(a.x, b.x); r.y = fminf(a.y, b.y); return r;
}
__device__ __forceinline__ v2f max2(v2f a, v2f b) {
    v2f r; r.x = fmaxf(a.x, b.x); r.y = fmaxf(a.y, b.y); return r;
}
__device__ __forceinline__ v2f rcp2(v2f a) {
    v2f r; r.x = __builtin_amdgcn_rcpf(a.x); r.y = __builtin_amdgcn_rcpf(a.y); return r;
}
__device__ __forceinline__ v2f exp22(v2f a) {
    v2f r; r.x = __builtin_amdgcn_exp2f(a.x); r.y = __builtin_amdgcn_exp2f(a.y); return r;
}

__global__ __launch_bounds__(BLK) void ciou_attn_kernel(
        const float* __restrict__ feat_row,
        const float* __restrict__ feat_pair,
        float* __restrict__ part) {
    __shared__ float jrec[NPAIR * 24];   // 3 KB, packed-SoA pair records
    const int tid = threadIdx.x;
    const int gb = blockIdx.x / JT;
    const int jt = blockIdx.x % JT;
    const int i = gb * BLK + tid;

    // Stage 32 pair-records (768 floats = 192 float4s) straight from global.
    if (tid < 192) {
        ((float4*)jrec)[tid] =
            ((const float4*)(feat_pair + (size_t)jt * NPAIR * 24))[tid];
    }

    // Row record: 3 coalesced float4 loads.
    const float4* rp = (const float4*)(feat_row + (size_t)i * 12);
    const float4 r0 = rp[0], r1 = rp[1], r2 = rp[2];
    const float rx1 = r0.x, ry1 = r0.y, rx2 = r0.z, ry2 = r0.w;
    const float rhx = r1.x, rhy = r1.y, rw = r1.z, rh = r1.w;
    const float rareps = r2.x, rat = r2.y, rcf2 = r2.z;

    __syncthreads();

    v2f sum = 0.f, a0 = 0.f, a1 = 0.f, a2 = 0.f, a3 = 0.f, a4 = 0.f;
    const float ONEP = 1.f + FEPS;

#pragma unroll 4
    for (int p = 0; p < NPAIR; p++) {
        const float* f = &jrec[p * 24];   // uniform addr -> broadcast reads
        const v2f X1 = *(const v2f*)(f + 0),  Y1 = *(const v2f*)(f + 2);
        const v2f X2 = *(const v2f*)(f + 4),  Y2 = *(const v2f*)(f + 6);
        const v2f HX = *(const v2f*)(f + 8),  HY = *(const v2f*)(f + 10);
        const v2f W  = *(const v2f*)(f + 12), H  = *(const v2f*)(f + 14);
        const v2f AR = *(const v2f*)(f + 16), AT = *(const v2f*)(f + 18);
        const v2f CF2 = *(const v2f*)(f + 20), CF = *(const v2f*)(f + 22);

        v2f iwr = min2(rx2, X2) - max2(rx1, X1);
        v2f ihr = min2(ry2, Y2) - max2(ry1, Y1);
        v2f inter = max2(iwr, 0.f) * max2(ihr, 0.f);
        v2f uni = (rareps + AR) - inter;
        v2f cw = (rw + W) - iwr;             // enclosing box identity
        v2f chh = (rh + H) - ihr;
        v2f c2 = cw * cw + chh * chh + FEPS;
        v2f dx = HX - rhx;
        v2f dy = HY - rhy;
        v2f rho2 = dx * dx + dy * dy;        // /4 pre-folded
        v2f da = AT - rat;                   // 4/pi^2 pre-folded
        v2f v = da * da;
        v2f P = (v + ONEP) * uni - inter;    // den*uni
        P = max2(P, 1e-12f);                 // fp-cancellation guard
        v2f rr = rcp2(uni * c2 * P);         // one rcp per pair
        v2f t1 = inter * c2 - rho2 * uni;
        v2f vu = v * uni;
        v2f num = t1 * P - (vu * vu) * c2;
        v2f e = exp22((num * rr) * (rcf2 * CF2));
        sum += e;
        a0 += e * CF;
        a1 += e * X1;
        a2 += e * Y1;
        a3 += e * X2;
        a4 += e * Y2;
    }

    float* pp = part + (size_t)jt * N6 + (size_t)i * 6;
    pp[0] = sum.x + sum.y;
    pp[1] = a0.x + a0.y;
    pp[2] = a1.x + a1.y;
    pp[3] = a2.x + a2.y;
    pp[4] = a3.x + a3.y;
    pp[5] = a4.x + a4.y;
}

// One thread per output element (i,c): sum JT partials, softmax-divide, sigmoid.
__global__ void epilogue_kernel(const float* __restrict__ x,
                                const float* __restrict__ gamma,
                                const float* __restrict__ part,
                                float* __restrict__ out) {
    int idx = blockIdx.x * blockDim.x + threadIdx.x;
    if (idx >= N * 5) return;
    int i = idx / 5, c = idx % 5;
    float se = 0.f, a = 0.f;
    const float* p = part + (size_t)i * 6;
#pragma unroll 8
    for (int jt = 0; jt < JT; jt++) {
        se += p[jt * (size_t)N6 + 0];
        a  += p[jt * (size_t)N6 + 1 + c];
    }
    float xp = x[idx] * gamma[0] + a / se;
    out[idx] = 1.f / (1.f + expf(-xp));
}

extern "C" void kernel_launch(void* const* d_in, const int* in_sizes, int n_in,
                              void* d_out, int out_size, void* d_ws, size_t ws_size,
                              hipStream_t stream) {
    const float* x = (const float*)d_in[0];
    const float* gamma = (const float*)d_in[1];
    float* out = (float*)d_out;
    float* part = (float*)d_ws;                      // 6.29 MB
    float* feat_row = part + (size_t)JT * N6;        // 196 KB
    float* feat_pair = feat_row + (size_t)N * 12;    // 196 KB

    feat_kernel<<<(N + BLK - 1) / BLK, BLK, 0, stream>>>(x, feat_row, feat_pair);
    ciou_attn_kernel<<<(N / BLK) * JT, BLK, 0, stream>>>(feat_row, feat_pair, part);
    epilogue_kernel<<<(N * 5 + 255) / 256, 256, 0, stream>>>(x, gamma, part, out);
}

// Round 8
// 81.267 us; speedup vs baseline: 1.1698x; 1.0271x over previous
//
#include <hip/hip_runtime.h>
#include <math.h>

#define N 4096
#define FEPS 1e-7f
#define HEPS 5e-8f      // FEPS/2, split across the two records of a pair
#define BLK 256
#define JT 64           // grid = 16*64 = 1024 blocks = 4 blocks/CU = 4 waves/SIMD
#define CH 64           // j's per block
#define NPAIR (CH / 2)  // 32 packed j-pairs per block
#define KATAN 0.6366197723675814f   // 2/pi (folds 4/pi^2 into atan)
#define SQL2E 1.2011224087864498f   // sqrt(log2 e), folds exp->exp2 into conf

typedef float v2f __attribute__((ext_vector_type(2)));

// d_ws: part[jt][c][i] : JT*6*N floats = 6.29 MB. [c][i] innermost -> main's
// 6 partial stores AND epilogue's 128 partial loads are lane-contiguous.
//
// r8 (history: r0=83.9 r1=86.2 r2=95.9 r3=93.9 r4=83.7 r5=95.1 r6=91.2
// r7=83.5): r7 HALVED inner-loop instructions -> -0.2us. With r0/r4/r7
// within 0.5us across radically different loops, the main kernel must be
// SMALL (~8-12us), not ~35us; the invariant ~43us (after the fixed 41us
// harness poison fill) is mostly feat+epilogue+3 launch gaps + the
// uncoalesced 6.3MB partials round-trip (writes at 24B/lane stride; reads
// at 98KB stride). r8 attacks exactly that, keeping r7's measured-best
// inner loop bit-identical:
//   1. feat fused into main (r0 measured this ~free at JT=64) -> 2 kernels.
//   2. part[jt][c][i] layout -> coalesced writes.
//   3. epilogue thread map (c,i)=(idx/N, idx%N) -> coalesced reads.
//
// Kept (absmax=0 through r7): packed-v2f one-rcp common-denominator CIoU:
//   P=(v+1+eps)*uni-inter (=den*uni, clamp>=1e-12; cancels in the ratio on
//   the diagonal), ciou=[P*(inter*c2-rho2*uni)-v^2*uni^2*c2]/(uni*c2*P);
// eps split across records, 4/pi^2 folded into atan, log2e folded into conf.
// NO 2nd __launch_bounds__ arg (measured: forcing waves/EU spills/regresses).

__device__ __forceinline__ v2f min2(v2f a, v2f b) {
    v2f r; r.x = fminf(a.x, b.x); r.y = fminf(a.y, b.y); return r;
}
__device__ __forceinline__ v2f max2(v2f a, v2f b) {
    v2f r; r.x = fmaxf(a.x, b.x); r.y = fmaxf(a.y, b.y); return r;
}
__device__ __forceinline__ v2f rcp2(v2f a) {
    v2f r; r.x = __builtin_amdgcn_rcpf(a.x); r.y = __builtin_amdgcn_rcpf(a.y); return r;
}
__device__ __forceinline__ v2f exp22(v2f a) {
    v2f r; r.x = __builtin_amdgcn_exp2f(a.x); r.y = __builtin_amdgcn_exp2f(a.y); return r;
}

// Packed-SoA pair records in LDS: field k of pair p, slot s (s=j&1) at
// jrec[p*24 + k*2 + s]. Fields: 0:x1 1:y1 2:x2 3:y2 4:hx 5:hy 6:w 7:h
// 8:area+eps/2 9:atan-folded 10:cf*sqrt(log2e) 11:cf
__global__ __launch_bounds__(BLK) void ciou_attn_kernel(
        const float* __restrict__ x,
        float* __restrict__ part) {
    __shared__ float jrec[NPAIR * 24];   // 3 KB
    const int tid = threadIdx.x;
    const int gb = blockIdx.x / JT;
    const int jt = blockIdx.x % JT;
    const int i = gb * BLK + tid;

    // Stage j-chunk in-kernel (first CH threads; one atanf each).
    if (tid < CH) {
        int j = jt * CH + tid;
        float cf = x[j * 5 + 0], jx1 = x[j * 5 + 1], jy1 = x[j * 5 + 2];
        float jx2 = x[j * 5 + 3], jy2 = x[j * 5 + 4];
        float w = jx2 - jx1, h = jy2 - jy1;
        float* dp = &jrec[(tid >> 1) * 24 + (tid & 1)];
        dp[0]  = jx1;               dp[2]  = jy1;
        dp[4]  = jx2;               dp[6]  = jy2;
        dp[8]  = (jx1 + jx2) * 0.5f; dp[10] = (jy1 + jy2) * 0.5f;
        dp[12] = w;                 dp[14] = h;
        dp[16] = fmaf(w, h, HEPS);
        dp[18] = KATAN * atanf(w / (h + FEPS));
        dp[20] = cf * SQL2E;        dp[22] = cf;
    }

    // Per-lane row record (in-registers; measured ~free vs precompute).
    const float rx1 = x[i * 5 + 1], ry1 = x[i * 5 + 2];
    const float rx2 = x[i * 5 + 3], ry2 = x[i * 5 + 4];
    const float rw = rx2 - rx1, rh = ry2 - ry1;
    const float rhx = (rx1 + rx2) * 0.5f, rhy = (ry1 + ry2) * 0.5f;
    const float rareps = fmaf(rw, rh, HEPS);
    const float rat = KATAN * atanf(rw / (rh + FEPS));
    const float rcf2 = x[i * 5 + 0] * SQL2E;

    __syncthreads();

    v2f sum = 0.f, a0 = 0.f, a1 = 0.f, a2 = 0.f, a3 = 0.f, a4 = 0.f;
    const float ONEP = 1.f + FEPS;

#pragma unroll 4
    for (int p = 0; p < NPAIR; p++) {
        const float* f = &jrec[p * 24];   // uniform addr -> broadcast reads
        const v2f X1 = *(const v2f*)(f + 0),  Y1 = *(const v2f*)(f + 2);
        const v2f X2 = *(const v2f*)(f + 4),  Y2 = *(const v2f*)(f + 6);
        const v2f HX = *(const v2f*)(f + 8),  HY = *(const v2f*)(f + 10);
        const v2f W  = *(const v2f*)(f + 12), H  = *(const v2f*)(f + 14);
        const v2f AR = *(const v2f*)(f + 16), AT = *(const v2f*)(f + 18);
        const v2f CF2 = *(const v2f*)(f + 20), CF = *(const v2f*)(f + 22);

        v2f iwr = min2(rx2, X2) - max2(rx1, X1);
        v2f ihr = min2(ry2, Y2) - max2(ry1, Y1);
        v2f inter = max2(iwr, 0.f) * max2(ihr, 0.f);
        v2f uni = (rareps + AR) - inter;
        v2f cw = (rw + W) - iwr;             // enclosing box identity
        v2f chh = (rh + H) - ihr;
        v2f c2 = cw * cw + chh * chh + FEPS;
        v2f dx = HX - rhx;
        v2f dy = HY - rhy;
        v2f rho2 = dx * dx + dy * dy;        // /4 pre-folded
        v2f da = AT - rat;                   // 4/pi^2 pre-folded
        v2f v = da * da;
        v2f P = (v + ONEP) * uni - inter;    // den*uni
        P = max2(P, 1e-12f);                 // fp-cancellation guard
        v2f rr = rcp2(uni * c2 * P);         // one rcp per pair
        v2f t1 = inter * c2 - rho2 * uni;
        v2f vu = v * uni;
        v2f num = t1 * P - (vu * vu) * c2;
        v2f e = exp22((num * rr) * (rcf2 * CF2));
        sum += e;
        a0 += e * CF;
        a1 += e * X1;
        a2 += e * Y1;
        a3 += e * X2;
        a4 += e * Y2;
    }

    // Coalesced partial stores: [jt][c][i], lanes contiguous in i.
    float* p = part + (size_t)jt * 6 * N;
    p[0 * N + i] = sum.x + sum.y;
    p[1 * N + i] = a0.x + a0.y;
    p[2 * N + i] = a1.x + a1.y;
    p[3 * N + i] = a2.x + a2.y;
    p[4 * N + i] = a3.x + a3.y;
    p[5 * N + i] = a4.x + a4.y;
}

// Transposed thread map: consecutive threads = consecutive i, same c ->
// every partial load is wave-coalesced. x/out accesses are strided (20B)
// but total only 80KB each.
__global__ void epilogue_kernel(const float* __restrict__ x,
                                const float* __restrict__ gamma,
                                const float* __restrict__ part,
                                float* __restrict__ out) {
    int idx = blockIdx.x * blockDim.x + threadIdx.x;
    if (idx >= N * 5) return;
    int c = idx / N, i = idx - c * N;
    float se = 0.f, a = 0.f;
#pragma unroll 8
    for (int jt = 0; jt < JT; jt++) {
        const float* p = part + (size_t)jt * 6 * N;
        se += p[0 * N + i];
        a  += p[(1 + c) * N + i];
    }
    float xp = x[i * 5 + c] * gamma[0] + a / se;
    out[i * 5 + c] = 1.f / (1.f + expf(-xp));
}

extern "C" void kernel_launch(void* const* d_in, const int* in_sizes, int n_in,
                              void* d_out, int out_size, void* d_ws, size_t ws_size,
                              hipStream_t stream) {
    const float* x = (const float*)d_in[0];
    const float* gamma = (const float*)d_in[1];
    float* out = (float*)d_out;
    float* part = (float*)d_ws;  // JT*6*N floats = 6.29 MB

    ciou_attn_kernel<<<(N / BLK) * JT, BLK, 0, stream>>>(x, part);
    epilogue_kernel<<<(N * 5 + 255) / 256, 256, 0, stream>>>(x, gamma, part, out);
}